// Round 1
// baseline (288.234 us; speedup 1.0000x reference)
//
#include <hip/hip_runtime.h>
#include <stdint.h>

// KmeansAudioQuantizer on MI355X (gfx950)
// B=8, L=1024, C=1024, N=5000.  M = B*L = 8192 queries.
//
// Pipeline:
//   1) convert_z: z (f32) -> bf16
//   2) prep_cb:  codebook -> bf16 (padded to 5120 rows w/ zeros) + exact f32 c2[n]
//   3) gemm_score: score[m][n] = c2[n] - 2 * z[m].c[n]  (bf16 MFMA, f32 out to ws)
//   4) argmin_gather: per-row approx min -> margin candidates -> f64 exact rescore
//      -> write indices (as float) + masked gathered codebook rows + loss=0

#define M_TOTAL 8192
#define K_DIM   1024
#define N_REAL  5000
#define N_PAD   5120

typedef __attribute__((ext_vector_type(8))) short bf16x8;
typedef __attribute__((ext_vector_type(4))) float f32x4;

__device__ __forceinline__ ushort f2bf(float x) {
  union { float f; uint32_t u; } v; v.f = x;
  uint32_t r = v.u + 0x7FFFu + ((v.u >> 16) & 1u);   // round-to-nearest-even
  return (ushort)(r >> 16);
}

__device__ __forceinline__ void async16(void* lds, const void* g) {
  __builtin_amdgcn_global_load_lds(
      (const __attribute__((address_space(1))) void*)g,
      (__attribute__((address_space(3))) void*)lds, 16, 0, 0);
}

// ---------------------------------------------------------------- prep kernels

__global__ __launch_bounds__(256) void convert_z(const float4* __restrict__ z4,
                                                 ushort* __restrict__ zb, int n4) {
  int i = blockIdx.x * blockDim.x + threadIdx.x;
  int stride = gridDim.x * blockDim.x;
  for (; i < n4; i += stride) {
    float4 v = z4[i];
    ushort4 u;
    u.x = f2bf(v.x); u.y = f2bf(v.y); u.z = f2bf(v.z); u.w = f2bf(v.w);
    *(ushort4*)&zb[(size_t)i * 4] = u;
  }
}

__global__ __launch_bounds__(256) void prep_cb(const float* __restrict__ cb,
                                               ushort* __restrict__ cbb,
                                               float* __restrict__ c2) {
  __shared__ float sred[4];
  const int row = blockIdx.x;       // 0..5119
  const int tid = threadIdx.x;
  if (row >= N_REAL) {              // zero pad rows so GEMM reads are benign
    ushort4 zz; zz.x = zz.y = zz.z = zz.w = 0;
    *(ushort4*)&cbb[(size_t)row * K_DIM + tid * 4] = zz;
    if (tid == 0) c2[row] = 0.f;
    return;
  }
  float4 v = ((const float4*)(cb + (size_t)row * K_DIM))[tid];
  ushort4 u;
  u.x = f2bf(v.x); u.y = f2bf(v.y); u.z = f2bf(v.z); u.w = f2bf(v.w);
  *(ushort4*)&cbb[(size_t)row * K_DIM + tid * 4] = u;
  float s = v.x * v.x + v.y * v.y + v.z * v.z + v.w * v.w;
  #pragma unroll
  for (int off = 32; off; off >>= 1) s += __shfl_down(s, off);
  int wv = tid >> 6, ln = tid & 63;
  if (ln == 0) sred[wv] = s;
  __syncthreads();
  if (tid == 0) c2[row] = sred[0] + sred[1] + sred[2] + sred[3];
}

// ---------------------------------------------------------------- GEMM (score)
// 128x128 tile, BK=64, 4 waves (2x2 of 64x64), 16x16x32 bf16 MFMA.
// A = z_bf16 [8192][1024], B = cb_bf16 [5120][1024] (both K-major -> C = A.B^T)

__global__ __launch_bounds__(256) void gemm_score(const ushort* __restrict__ A,
                                                  const ushort* __restrict__ Bm,
                                                  const float* __restrict__ c2,
                                                  float* __restrict__ dist,
                                                  int rowBase) {
  __shared__ ushort sA[128 * 64];
  __shared__ ushort sB[128 * 64];
  const int tid  = threadIdx.x;
  const int wave = tid >> 6, lane = tid & 63;
  const int wm = wave >> 1, wn = wave & 1;
  const int tM = rowBase + blockIdx.y * 128;   // global A row
  const int tN = blockIdx.x * 128;             // codebook row

  f32x4 acc[4][4];
  #pragma unroll
  for (int i = 0; i < 4; ++i)
    #pragma unroll
    for (int j = 0; j < 4; ++j)
      acc[i][j] = (f32x4)0.f;

  char* sAb = (char*)sA;
  char* sBb = (char*)sB;
  const int o = tid * 16;                      // byte offset within 16KB tile

  for (int k0 = 0; k0 < K_DIM; k0 += 64) {
    __syncthreads();                           // protect LDS from prev readers
    #pragma unroll
    for (int it = 0; it < 4; ++it) {
      int ob = o + it * 4096;                  // 0..16383
      int r  = ob >> 7;                        // tile row (128B per row)
      int cbyte = ob & 127;
      const char* ga = (const char*)A + ((size_t)(tM + r) * K_DIM + k0) * 2 + cbyte;
      async16(sAb + ob, ga);
      const char* gb = (const char*)Bm + ((size_t)(tN + r) * K_DIM + k0) * 2 + cbyte;
      async16(sBb + ob, gb);
    }
    __syncthreads();                           // drains vmcnt before barrier
    #pragma unroll
    for (int kk = 0; kk < 2; ++kk) {
      bf16x8 af[4], bfr[4];
      const int kcol = kk * 32 + (lane >> 4) * 8;
      #pragma unroll
      for (int f = 0; f < 4; ++f) {
        int ra = wm * 64 + f * 16 + (lane & 15);
        af[f]  = *(const bf16x8*)&sA[ra * 64 + kcol];
        int rb = wn * 64 + f * 16 + (lane & 15);
        bfr[f] = *(const bf16x8*)&sB[rb * 64 + kcol];
      }
      #pragma unroll
      for (int i = 0; i < 4; ++i)
        #pragma unroll
        for (int j = 0; j < 4; ++j)
          acc[i][j] = __builtin_amdgcn_mfma_f32_16x16x32_bf16(af[i], bfr[j], acc[i][j], 0, 0, 0);
    }
  }

  // epilogue: score = c2[n] - 2*cross ; C/D layout col=lane&15, row=(lane>>4)*4+r
  const int cl = lane & 15, rg = lane >> 4;
  const int mBaseLocal = blockIdx.y * 128 + wm * 64;   // row local to chunk
  #pragma unroll
  for (int j = 0; j < 4; ++j) {
    int n = tN + wn * 64 + j * 16 + cl;
    float c2n = c2[n];
    #pragma unroll
    for (int i = 0; i < 4; ++i) {
      #pragma unroll
      for (int r = 0; r < 4; ++r) {
        int m = mBaseLocal + i * 16 + rg * 4 + r;
        dist[(size_t)m * N_PAD + n] = c2n - 2.0f * acc[i][j][r];
      }
    }
  }
}

// ------------------------------------------------------------- argmin + gather

__global__ __launch_bounds__(256) void argmin_gather(const float* __restrict__ dist,
                                                     const float* __restrict__ z,
                                                     const float* __restrict__ cb,
                                                     const int* __restrict__ mask,
                                                     float* __restrict__ out_q,
                                                     float* __restrict__ out_i,
                                                     float* __restrict__ out_loss,
                                                     int rowBase) {
  __shared__ __align__(16) float srow[N_REAL];
  __shared__ float swv[4];
  __shared__ int   swi[4];
  __shared__ float sminv;
  __shared__ int   scand[64];
  __shared__ int   scnt;
  __shared__ double sdv[4];
  __shared__ double sbestd;
  __shared__ int    sbesti;

  const int tid = threadIdx.x;
  const int ml  = blockIdx.x;            // row within chunk
  const int mg  = rowBase + ml;          // global query row
  const float* row = dist + (size_t)ml * N_PAD;

  // pass 1: stage row in LDS + thread-local lex-min (only n < 5000 scanned)
  float bestv = 3.4e38f; int besti = 0x7fffffff;
  for (int i = tid; i < N_REAL / 4; i += 256) {
    float4 v = ((const float4*)row)[i];
    ((float4*)srow)[i] = v;
    int b = i * 4;
    if (v.x < bestv) { bestv = v.x; besti = b; }
    if (v.y < bestv) { bestv = v.y; besti = b + 1; }
    if (v.z < bestv) { bestv = v.z; besti = b + 2; }
    if (v.w < bestv) { bestv = v.w; besti = b + 3; }
  }
  #pragma unroll
  for (int off = 32; off; off >>= 1) {
    float ov = __shfl_down(bestv, off);
    int   oi = __shfl_down(besti, off);
    if (ov < bestv || (ov == bestv && oi < besti)) { bestv = ov; besti = oi; }
  }
  const int wv = tid >> 6, ln = tid & 63;
  if (ln == 0) { swv[wv] = bestv; swi[wv] = besti; }
  __syncthreads();
  if (tid == 0) {
    float bv = swv[0]; int bi = swi[0];
    for (int w = 1; w < 4; ++w)
      if (swv[w] < bv || (swv[w] == bv && swi[w] < bi)) { bv = swv[w]; bi = swi[w]; }
    sminv = bv; scnt = 0;
  }
  __syncthreads();

  // pass 2: candidates within margin of approx min
  const float thr = sminv + 8.0f;
  for (int i = tid; i < N_REAL; i += 256) {
    if (srow[i] <= thr) {
      int p = atomicAdd(&scnt, 1);
      if (p < 64) scand[p] = i;
    }
  }
  __syncthreads();
  int nc = scnt < 64 ? scnt : 64;

  // pass 3: exact f64 rescore: sum c*(c - 2z) = c2 - 2*dot
  if (tid == 0) { sbestd = 1e300; sbesti = 0x7fffffff; }
  __syncthreads();
  const float* zr = z + (size_t)mg * K_DIM;
  for (int c = 0; c < nc; ++c) {
    int n = scand[c];
    const float* cr = cb + (size_t)n * K_DIM;
    float4 cv = ((const float4*)cr)[tid];
    float4 zv = ((const float4*)zr)[tid];
    double lsum = (double)cv.x * ((double)cv.x - 2.0 * (double)zv.x)
                + (double)cv.y * ((double)cv.y - 2.0 * (double)zv.y)
                + (double)cv.z * ((double)cv.z - 2.0 * (double)zv.z)
                + (double)cv.w * ((double)cv.w - 2.0 * (double)zv.w);
    #pragma unroll
    for (int off = 32; off; off >>= 1) lsum += __shfl_down(lsum, off);
    if (ln == 0) sdv[wv] = lsum;
    __syncthreads();
    if (tid == 0) {
      double s = sdv[0] + sdv[1] + sdv[2] + sdv[3];
      if (s < sbestd || (s == sbestd && n < sbesti)) { sbestd = s; sbesti = n; }
    }
    __syncthreads();
  }

  // pass 4: outputs
  const int bidx = sbesti;
  if (tid == 0) out_i[mg] = (float)bidx;
  const int mk = mask[mg];
  float4 qz; qz.x = qz.y = qz.z = qz.w = 0.f;
  float4 src = ((const float4*)(cb + (size_t)bidx * K_DIM))[tid];
  ((float4*)(out_q + (size_t)mg * K_DIM))[tid] = mk ? src : qz;
  if (mg == 0 && tid == 0) *out_loss = 0.0f;
}

// -------------------------------------------------------------------- launcher

extern "C" void kernel_launch(void* const* d_in, const int* in_sizes, int n_in,
                              void* d_out, int out_size, void* d_ws, size_t ws_size,
                              hipStream_t stream) {
  const float* z    = (const float*)d_in[0];
  const int*   mask = (const int*)d_in[1];
  const float* cb   = (const float*)d_in[2];

  float* out      = (float*)d_out;
  float* out_q    = out;                                   // [8192][1024]
  float* out_i    = out + (size_t)M_TOTAL * K_DIM;         // [8192] (as float)
  float* out_loss = out_i + M_TOTAL;                       // [1]

  char* ws = (char*)d_ws;
  ushort* zb   = (ushort*)(ws);                            // 16,777,216 B
  ushort* cbb  = (ushort*)(ws + 16777216);                 // 10,485,760 B
  float*  c2   = (float*)(ws + 27262976);                  //     20,480 B
  float*  dist = (float*)(ws + 27283456);                  // chunkM * 5120 * 4 B

  const size_t fixed = 27283456;
  size_t avail = (ws_size > fixed) ? (ws_size - fixed) : 0;
  long long cmax = (long long)(avail / ((size_t)N_PAD * 4));
  int chunkM = (int)((cmax / 128) * 128);
  if (chunkM > M_TOTAL) chunkM = M_TOTAL;
  if (chunkM < 128) chunkM = 128;     // below this ws is unusably small anyway

  convert_z<<<2048, 256, 0, stream>>>((const float4*)z, zb, (M_TOTAL * K_DIM) / 4);
  prep_cb<<<N_PAD, 256, 0, stream>>>(cb, cbb, c2);

  for (int cs = 0; cs < M_TOTAL; cs += chunkM) {
    int cm = (chunkM < M_TOTAL - cs) ? chunkM : (M_TOTAL - cs);
    dim3 g(N_PAD / 128, cm / 128);
    gemm_score<<<g, 256, 0, stream>>>(zb, cbb, c2, dist, cs);
    argmin_gather<<<cm, 256, 0, stream>>>(dist, z, cb, mask, out_q, out_i, out_loss, cs);
  }
}